// Round 1
// baseline (272.180 us; speedup 1.0000x reference)
//
#include <hip/hip_runtime.h>

#define N_ROWS 8192
#define DIM 64
#define EPS 1e-8f
#define LOG2E 1.4426950408889634f
#define SHIFT 64.0f                      // accumulate exp terms scaled by 2^64
#define SHIFT_LN 44.361419555836499802f  // 64 * ln(2)
#define JSPLIT 32
#define JCHUNK (N_ROWS / JSPLIT)         // 256

// ws layout (floats): [0,8192) top_scaled | [8192,16384) bot_scaled | [16384,24576) sq
// total 96 KB

__global__ void snn_zero(float* __restrict__ ws) {
    int t = blockIdx.x * blockDim.x + threadIdx.x;
    if (t < 2 * N_ROWS) ws[t] = 0.0f;
}

// one wave (64 lanes) per row; DIM==64 so lane k holds x[row][k]
__global__ void snn_rowsq(const float* __restrict__ x, float* __restrict__ sq) {
    int wave = (blockIdx.x * blockDim.x + threadIdx.x) >> 6;
    int lane = threadIdx.x & 63;
    if (wave < N_ROWS) {
        float v = x[(size_t)wave * DIM + lane];
        float s = v * v;
        #pragma unroll
        for (int off = 32; off > 0; off >>= 1) s += __shfl_xor(s, off, 64);
        if (lane == 0) sq[wave] = s;
    }
}

__global__ __launch_bounds__(256, 4) void snn_main(
    const float* __restrict__ x, const int* __restrict__ y,
    const float* __restrict__ w, const float* __restrict__ sq,
    float* __restrict__ top, float* __restrict__ bot)
{
    const int i = blockIdx.x * 256 + threadIdx.x;   // row this thread owns
    // x_i into 64 VGPRs
    float xi[DIM];
    #pragma unroll
    for (int k = 0; k < DIM / 4; k++) {
        float4 v = ((const float4*)(x + (size_t)i * DIM))[k];
        xi[4 * k + 0] = v.x; xi[4 * k + 1] = v.y;
        xi[4 * k + 2] = v.z; xi[4 * k + 3] = v.w;
    }
    const float sqi = sq[i];
    const int   yi  = y[i];
    const float c1  = -w[0] * LOG2E;   // uniform (s_load)
    const int   j0  = blockIdx.y * JCHUNK;

    float ts = 0.0f, bs = 0.0f;
    for (int jj = 0; jj < JCHUNK; jj++) {
        const int j = j0 + jj;                       // wave-uniform
        const float* __restrict__ xj = x + (size_t)j * DIM;  // uniform -> s_load
        float d0 = 0.f, d1 = 0.f, d2 = 0.f, d3 = 0.f;
        #pragma unroll
        for (int k = 0; k < DIM; k += 4) {
            d0 = fmaf(xj[k + 0], xi[k + 0], d0);
            d1 = fmaf(xj[k + 1], xi[k + 1], d1);
            d2 = fmaf(xj[k + 2], xi[k + 2], d2);
            d3 = fmaf(xj[k + 3], xi[k + 3], d3);
        }
        float dot = (d0 + d1) + (d2 + d3);
        float dd  = fmaf(-2.0f, dot, sqi + sq[j]);   // sq[j] uniform -> s_load
        dd = fmaxf(dd, 0.0f);
        float dist = __builtin_amdgcn_sqrtf(dd);
        float e2   = exp2f(fmaf(c1, dist, SHIFT));   // exp(-w*dist) * 2^64
        bool offd = (j != i);
        bool same = offd && (y[j] == yi);
        bs += offd ? e2 : 0.0f;
        ts += same ? e2 : 0.0f;
    }
    atomicAdd(&top[i], ts);
    atomicAdd(&bot[i], bs);
}

__global__ __launch_bounds__(256) void snn_final(
    const float* __restrict__ top, const float* __restrict__ bot,
    float* __restrict__ out)
{
    __shared__ float red[256];
    float acc = 0.0f;
    for (int i = threadIdx.x; i < N_ROWS; i += 256) {
        float t = top[i];                    // top * 2^64, always normal fp32
        float b = bot[i] * 0x1p-64f + EPS;   // bot ~1e-24 max; +eps dominates
        acc += (logf(t) - SHIFT_LN) - logf(b);
    }
    red[threadIdx.x] = acc;
    __syncthreads();
    #pragma unroll
    for (int s = 128; s > 0; s >>= 1) {
        if (threadIdx.x < s) red[threadIdx.x] += red[threadIdx.x + s];
        __syncthreads();
    }
    if (threadIdx.x == 0) out[0] = -red[0] / (float)N_ROWS;
}

extern "C" void kernel_launch(void* const* d_in, const int* in_sizes, int n_in,
                              void* d_out, int out_size, void* d_ws, size_t ws_size,
                              hipStream_t stream) {
    const float* x = (const float*)d_in[0];
    const int*   y = (const int*)d_in[1];
    const float* w = (const float*)d_in[2];
    float* out = (float*)d_out;

    float* ws  = (float*)d_ws;
    float* top = ws;
    float* bot = ws + N_ROWS;
    float* sq  = ws + 2 * N_ROWS;

    snn_zero<<<(2 * N_ROWS + 255) / 256, 256, 0, stream>>>(ws);
    snn_rowsq<<<N_ROWS / 4, 256, 0, stream>>>(x, sq);
    snn_main<<<dim3(N_ROWS / 256, JSPLIT), 256, 0, stream>>>(x, y, w, sq, top, bot);
    snn_final<<<1, 256, 0, stream>>>(top, bot, out);
}

// Round 3
// 210.997 us; speedup vs baseline: 1.2900x; 1.2900x over previous
//
#include <hip/hip_runtime.h>

typedef float f32x2 __attribute__((ext_vector_type(2)));

#define N_ROWS 8192
#define DIM 64
#define EPS 1e-8f
#define LOG2E 1.4426950408889634f
#define SHIFT 64.0f                      // accumulate exp terms scaled by 2^64
#define SHIFT_LN 44.361419555836499802f  // 64 * ln(2)
#define JSPLIT 32
#define JCHUNK (N_ROWS / JSPLIT)         // 256

#define REP32(M) M(0) M(1) M(2) M(3) M(4) M(5) M(6) M(7) \
                 M(8) M(9) M(10) M(11) M(12) M(13) M(14) M(15) \
                 M(16) M(17) M(18) M(19) M(20) M(21) M(22) M(23) \
                 M(24) M(25) M(26) M(27) M(28) M(29) M(30) M(31)

// ws layout (floats): [0,8192) top_scaled | [8192,16384) bot_scaled | [16384,24576) sq

__global__ void snn_zero(float* __restrict__ ws, float* __restrict__ out) {
    int t = blockIdx.x * blockDim.x + threadIdx.x;
    if (t < 2 * N_ROWS) ws[t] = 0.0f;
    if (t == 0) out[0] = 0.0f;
}

// one wave (64 lanes) per row; DIM==64 so lane k holds x[row][k]
__global__ void snn_rowsq(const float* __restrict__ x, float* __restrict__ sq) {
    int wave = (blockIdx.x * blockDim.x + threadIdx.x) >> 6;
    int lane = threadIdx.x & 63;
    float v = x[(size_t)wave * DIM + lane];
    float s = v * v;
    #pragma unroll
    for (int off = 32; off > 0; off >>= 1) s += __shfl_xor(s, off, 64);
    if (lane == 0) sq[wave] = s;
}

__global__ __launch_bounds__(256, 4) void snn_main(
    const float* __restrict__ x, const int* __restrict__ y,
    const float* __restrict__ w, const float* __restrict__ sq,
    float* __restrict__ top, float* __restrict__ bot)
{
    const int i = blockIdx.x * 256 + threadIdx.x;   // row this thread owns
    const f32x2* __restrict__ xip = (const f32x2*)(x + (size_t)i * DIM);
    // 32 named float2 vars -> guaranteed VGPR residence (no SROA on big arrays)
#define DECL_XI(n) f32x2 xv##n = xip[n];
    REP32(DECL_XI)
#undef DECL_XI

    const float sqi = sq[i];
    const int   yi  = y[i];
    const float c1  = -w[0] * LOG2E;   // uniform (s_load)
    const int   j0  = blockIdx.y * JCHUNK;

    float ts = 0.0f, bs = 0.0f;
    for (int jj = 0; jj < JCHUNK; jj++) {
        const int j = j0 + jj;                                // wave-uniform
        const f32x2* __restrict__ xjp = (const f32x2*)(x + (size_t)j * DIM); // -> s_load
        f32x2 acc[4];
        acc[0] = (f32x2){0.f, 0.f}; acc[1] = acc[0];
        acc[2] = acc[0];            acc[3] = acc[0];
        // 32 packed fp32 FMAs (v_pk_fma_f32), one SGPR-pair operand each
#define FMA_T(n) acc[(n) & 3] = __builtin_elementwise_fma(xjp[n], xv##n, acc[(n) & 3]);
        REP32(FMA_T)
#undef FMA_T
        f32x2 s01 = acc[0] + acc[1];
        f32x2 s23 = acc[2] + acc[3];
        f32x2 sv  = s01 + s23;
        float dot = sv.x + sv.y;

        float dd  = fmaf(-2.0f, dot, sqi + sq[j]);
        dd = fmaxf(dd, 0.0f);
        float dist = __builtin_amdgcn_sqrtf(dd);
        float e2   = exp2f(fmaf(c1, dist, SHIFT));   // exp(-w*dist) * 2^64
        bool offd = (j != i);
        bool same = offd && (y[j] == yi);
        bs += offd ? e2 : 0.0f;
        ts += same ? e2 : 0.0f;
    }
    atomicAdd(&top[i], ts);
    atomicAdd(&bot[i], bs);
}

// 32 blocks x 256 threads; one row per thread, block-reduce, atomic into out
__global__ __launch_bounds__(256) void snn_final(
    const float* __restrict__ top, const float* __restrict__ bot,
    float* __restrict__ out)
{
    const int i = blockIdx.x * 256 + threadIdx.x;
    float t = top[i];                    // top * 2^64, normal fp32
    float b = bot[i] * 0x1p-64f + EPS;   // bot ~1e-24 max; +eps dominates
    float acc = (logf(t) - SHIFT_LN) - logf(b);
    // wave reduction
    #pragma unroll
    for (int off = 32; off > 0; off >>= 1) acc += __shfl_xor(acc, off, 64);
    __shared__ float red[4];
    const int wave = threadIdx.x >> 6;
    const int lane = threadIdx.x & 63;
    if (lane == 0) red[wave] = acc;
    __syncthreads();
    if (threadIdx.x == 0) {
        float s = red[0] + red[1] + red[2] + red[3];
        atomicAdd(out, -s / (float)N_ROWS);
    }
}

extern "C" void kernel_launch(void* const* d_in, const int* in_sizes, int n_in,
                              void* d_out, int out_size, void* d_ws, size_t ws_size,
                              hipStream_t stream) {
    const float* x = (const float*)d_in[0];
    const int*   y = (const int*)d_in[1];
    const float* w = (const float*)d_in[2];
    float* out = (float*)d_out;

    float* ws  = (float*)d_ws;
    float* top = ws;
    float* bot = ws + N_ROWS;
    float* sq  = ws + 2 * N_ROWS;

    snn_zero<<<(2 * N_ROWS + 255) / 256, 256, 0, stream>>>(ws, out);
    snn_rowsq<<<N_ROWS / 4, 256, 0, stream>>>(x, sq);
    snn_main<<<dim3(N_ROWS / 256, JSPLIT), 256, 0, stream>>>(x, y, w, sq, top, bot);
    snn_final<<<N_ROWS / 256, 256, 0, stream>>>(top, bot, out);
}

// Round 4
// 169.043 us; speedup vs baseline: 1.6101x; 1.2482x over previous
//
#include <hip/hip_runtime.h>

typedef _Float16 f16x8 __attribute__((ext_vector_type(8)));
typedef float    f32x4 __attribute__((ext_vector_type(4)));

#define N_ROWS 8192
#define DIM 64
#define EPS 1e-8f
#define LOG2E 1.4426950408889634f
#define SHIFT 64.0f                      // exp terms scaled by 2^64
#define SHIFT_LN 44.361419555836499802f  // 64 * ln(2)

// ws layout: [0,8192) top | [8192,16384) bot | [16384,24576) sq (floats)
// then xh (8192*64 f16), xl (8192*64 f16)  -> total ~2.2 MB

__global__ void snn_zero(float* __restrict__ ws, float* __restrict__ out) {
    int t = blockIdx.x * blockDim.x + threadIdx.x;
    if (t < 2 * N_ROWS) ws[t] = 0.0f;
    if (t == 0) out[0] = 0.0f;
}

// one wave per row: f16 split + squared norm
__global__ void snn_prep(const float* __restrict__ x, _Float16* __restrict__ xh,
                         _Float16* __restrict__ xl, float* __restrict__ sq) {
    int row  = (blockIdx.x * blockDim.x + threadIdx.x) >> 6;
    int lane = threadIdx.x & 63;
    float v = x[row * DIM + lane];
    _Float16 h = (_Float16)v;
    _Float16 l = (_Float16)(v - (float)h);
    xh[row * DIM + lane] = h;
    xl[row * DIM + lane] = l;
    float s = v * v;
    #pragma unroll
    for (int off = 32; off > 0; off >>= 1) s += __shfl_xor(s, off, 64);
    if (lane == 0) sq[row] = s;
}

// block = 4 waves in 2x2; wave tile = 64x64; block tile = 128x128
__global__ __launch_bounds__(256, 2) void snn_mfma(
    const _Float16* __restrict__ xh, const _Float16* __restrict__ xl,
    const float* __restrict__ sq, const int* __restrict__ y,
    const float* __restrict__ w,
    float* __restrict__ top, float* __restrict__ bot)
{
    __shared__ float lt[128], lb[128];
    const int tid = threadIdx.x, wv = tid >> 6, lane = tid & 63;
    if (tid < 128) { lt[tid] = 0.0f; lb[tid] = 0.0f; }
    __syncthreads();

    const int I0 = blockIdx.x * 128 + (wv & 1) * 64;
    const int J0 = blockIdx.y * 128 + (wv >> 1) * 64;
    const int mrow = lane & 15, kq = lane >> 4;
    const float c1 = -w[0] * LOG2E;

    // A fragments: 4 m-tiles x 2 k-chunks, hi & lo planes (resident, 64 VGPR)
    f16x8 ah[4][2], al[4][2];
    #pragma unroll
    for (int mt = 0; mt < 4; mt++)
        #pragma unroll
        for (int kc = 0; kc < 2; kc++) {
            int a = (I0 + mt * 16 + mrow) * DIM + kc * 32 + kq * 8;
            ah[mt][kc] = *(const f16x8*)(xh + a);
            al[mt][kc] = *(const f16x8*)(xl + a);
        }

    // per-lane row metadata: i = I0 + mt*16 + kq*4 + r
    float sqi[4][4]; int yi[4][4];
    #pragma unroll
    for (int mt = 0; mt < 4; mt++)
        #pragma unroll
        for (int r = 0; r < 4; r++) {
            int i = I0 + mt * 16 + kq * 4 + r;
            sqi[mt][r] = sq[i];
            yi[mt][r]  = y[i];
        }

    float ts[4][4], bs[4][4];
    #pragma unroll
    for (int mt = 0; mt < 4; mt++)
        #pragma unroll
        for (int r = 0; r < 4; r++) { ts[mt][r] = 0.0f; bs[mt][r] = 0.0f; }

    #pragma unroll
    for (int nt = 0; nt < 4; nt++) {
        const int jb = J0 + nt * 16;
        const int bbase = (jb + mrow) * DIM + kq * 8;
        f16x8 bh0 = *(const f16x8*)(xh + bbase);
        f16x8 bh1 = *(const f16x8*)(xh + bbase + 32);
        f16x8 bl0 = *(const f16x8*)(xl + bbase);
        f16x8 bl1 = *(const f16x8*)(xl + bbase + 32);
        const float sqj = sq[jb + mrow];   // this lane's column j
        const int   yj  = y[jb + mrow];
        const int   j   = jb + mrow;

        f32x4 acc[4];
        #pragma unroll
        for (int mt = 0; mt < 4; mt++) acc[mt] = (f32x4){0.f, 0.f, 0.f, 0.f};
        // hh
        #pragma unroll
        for (int mt = 0; mt < 4; mt++)
            acc[mt] = __builtin_amdgcn_mfma_f32_16x16x32_f16(ah[mt][0], bh0, acc[mt], 0, 0, 0);
        #pragma unroll
        for (int mt = 0; mt < 4; mt++)
            acc[mt] = __builtin_amdgcn_mfma_f32_16x16x32_f16(ah[mt][1], bh1, acc[mt], 0, 0, 0);
        // hl
        #pragma unroll
        for (int mt = 0; mt < 4; mt++)
            acc[mt] = __builtin_amdgcn_mfma_f32_16x16x32_f16(ah[mt][0], bl0, acc[mt], 0, 0, 0);
        #pragma unroll
        for (int mt = 0; mt < 4; mt++)
            acc[mt] = __builtin_amdgcn_mfma_f32_16x16x32_f16(ah[mt][1], bl1, acc[mt], 0, 0, 0);
        // lh
        #pragma unroll
        for (int mt = 0; mt < 4; mt++)
            acc[mt] = __builtin_amdgcn_mfma_f32_16x16x32_f16(al[mt][0], bh0, acc[mt], 0, 0, 0);
        #pragma unroll
        for (int mt = 0; mt < 4; mt++)
            acc[mt] = __builtin_amdgcn_mfma_f32_16x16x32_f16(al[mt][1], bh1, acc[mt], 0, 0, 0);

        // fused epilogue: d2 -> dist -> exp -> masked row-sums
        #pragma unroll
        for (int mt = 0; mt < 4; mt++)
            #pragma unroll
            for (int r = 0; r < 4; r++) {
                int i = I0 + mt * 16 + kq * 4 + r;
                float d2 = fmaf(-2.0f, acc[mt][r], sqi[mt][r] + sqj);
                d2 = fmaxf(d2, 0.0f);
                float dist = __builtin_amdgcn_sqrtf(d2);
                float e2 = exp2f(fmaf(c1, dist, SHIFT));
                bool offd = (i != j);
                bool same = offd && (yj == yi[mt][r]);
                bs[mt][r] += offd ? e2 : 0.0f;
                ts[mt][r] += same ? e2 : 0.0f;
            }
    }

    // reduce each slot across the 16 lanes sharing a row; accumulate in LDS
    #pragma unroll
    for (int mt = 0; mt < 4; mt++)
        #pragma unroll
        for (int r = 0; r < 4; r++) {
            float tv = ts[mt][r], bv = bs[mt][r];
            #pragma unroll
            for (int off = 1; off < 16; off <<= 1) {
                tv += __shfl_xor(tv, off, 64);
                bv += __shfl_xor(bv, off, 64);
            }
            if ((lane & 15) == 0) {
                int rl = (wv & 1) * 64 + mt * 16 + kq * 4 + r;
                atomicAdd(&lt[rl], tv);
                atomicAdd(&lb[rl], bv);
            }
        }
    __syncthreads();
    if (tid < 128) {
        atomicAdd(&top[blockIdx.x * 128 + tid], lt[tid]);
        atomicAdd(&bot[blockIdx.x * 128 + tid], lb[tid]);
    }
}

__global__ __launch_bounds__(256) void snn_final(
    const float* __restrict__ top, const float* __restrict__ bot,
    float* __restrict__ out)
{
    const int i = blockIdx.x * 256 + threadIdx.x;
    float t = top[i];                    // top * 2^64, normal fp32
    float b = bot[i] * 0x1p-64f + EPS;   // bot tiny; +eps dominates
    float acc = (logf(t) - SHIFT_LN) - logf(b);
    #pragma unroll
    for (int off = 32; off > 0; off >>= 1) acc += __shfl_xor(acc, off, 64);
    __shared__ float red[4];
    if ((threadIdx.x & 63) == 0) red[threadIdx.x >> 6] = acc;
    __syncthreads();
    if (threadIdx.x == 0) {
        float s = red[0] + red[1] + red[2] + red[3];
        atomicAdd(out, -s / (float)N_ROWS);
    }
}

extern "C" void kernel_launch(void* const* d_in, const int* in_sizes, int n_in,
                              void* d_out, int out_size, void* d_ws, size_t ws_size,
                              hipStream_t stream) {
    const float* x = (const float*)d_in[0];
    const int*   y = (const int*)d_in[1];
    const float* w = (const float*)d_in[2];
    float* out = (float*)d_out;

    float* ws  = (float*)d_ws;
    float* top = ws;
    float* bot = ws + N_ROWS;
    float* sq  = ws + 2 * N_ROWS;
    _Float16* xh = (_Float16*)(ws + 3 * N_ROWS);
    _Float16* xl = xh + (size_t)N_ROWS * DIM;

    snn_zero<<<(2 * N_ROWS + 255) / 256, 256, 0, stream>>>(ws, out);
    snn_prep<<<N_ROWS / 4, 256, 0, stream>>>(x, xh, xl, sq);
    snn_mfma<<<dim3(N_ROWS / 128, N_ROWS / 128), 256, 0, stream>>>(xh, xl, sq, y, w, top, bot);
    snn_final<<<N_ROWS / 256, 256, 0, stream>>>(top, bot, out);
}